// Round 5
// baseline (1148.421 us; speedup 1.0000x reference)
//
#include <hip/hip_runtime.h>
#include <hip/hip_bf16.h>

#define N_NODES 100000
#define N_EDGES 3200000
#define IN_F 512
#define HID 64
#define OUT_F 64
#define K_HOPS 10
#define N_SCAN_BLOCKS ((N_NODES + 255) / 256)   // 391

// histogram geometry: 4 ranges of 32768 bins cover 131072 >= N_NODES
#define HIST_BLOCKS 64
#define HIST_BINS 32768
#define HIST_WORDS (HIST_BINS / 2)              // 16384 packed dual-uint16 words
#define EDGES_PER_HIST_BLOCK (N_EDGES / HIST_BLOCKS)  // 50000
// scatter geometry: 8 sub-ranges of 16384 bins (64KB LDS cursor each)
#define SC_BINS 16384

typedef __attribute__((ext_vector_type(8))) short bf16x8;
typedef __attribute__((ext_vector_type(4))) float f32x4;

static __device__ __forceinline__ unsigned short f2bf(float f) {
    unsigned int u = __float_as_uint(f);
    u += 0x7FFFu + ((u >> 16) & 1u);            // round-to-nearest-even
    return (unsigned short)(u >> 16);
}
static __device__ __forceinline__ float bf2f(unsigned short s) {
    return __uint_as_float(((unsigned int)s) << 16);
}

// ---------------------------------------------------------------------------
__global__ void detect_i32_kernel(const unsigned int* ei_words, int* flag_is32) {
    int i = blockIdx.x * blockDim.x + threadIdx.x;  // 0..1023
    unsigned int w = ei_words[2 * i + 1];
    if (w != 0u) atomicOr(flag_is32, 1);
}

__global__ void __launch_bounds__(256) convert_kernel(const void* ei_raw, const int* flag_is32,
                                                      int* __restrict__ src32,
                                                      int* __restrict__ dst32) {
    int t = blockIdx.x * blockDim.x + threadIdx.x;     // 0 .. N_EDGES/2-1
    if (t >= N_EDGES / 2) return;
    if (*flag_is32) {
        const int2* ei = (const int2*)ei_raw;
        *(int2*)(src32 + 2 * t) = ei[t];
        *(int2*)(dst32 + 2 * t) = ei[N_EDGES / 2 + t];
    } else {
        const longlong2* ei = (const longlong2*)ei_raw;
        longlong2 s = ei[t];
        longlong2 d = ei[N_EDGES / 2 + t];
        *(int2*)(src32 + 2 * t) = make_int2((int)s.x, (int)s.y);
        *(int2*)(dst32 + 2 * t) = make_int2((int)d.x, (int)d.y);
    }
}

// Partial histograms of one index array in LDS (packed dual-uint16).
// grid = (HIST_BLOCKS edge slices, 4 ranges).
__global__ void __launch_bounds__(256) hist_kernel(const int* __restrict__ a,
                                                   unsigned int* __restrict__ partials) {
    __shared__ unsigned int cnt[HIST_WORDS];   // 64 KB
    int tid = threadIdx.x;
    for (int w = tid; w < HIST_WORDS; w += 256) cnt[w] = 0u;
    __syncthreads();

    int range = blockIdx.y;
    unsigned lo = (unsigned)(range * HIST_BINS);
    int beg = blockIdx.x * EDGES_PER_HIST_BLOCK;
    int end = beg + EDGES_PER_HIST_BLOCK;
    for (int i = beg + tid; i < end; i += 256) {
        unsigned v = (unsigned)a[i] - lo;
        if (v < HIST_BINS) atomicAdd(&cnt[v >> 1], 1u << ((v & 1u) * 16u));
    }
    __syncthreads();

    unsigned int* outp = partials + ((size_t)(blockIdx.y * HIST_BLOCKS + blockIdx.x)) * HIST_WORDS;
    for (int w = tid; w < HIST_WORDS / 4; w += 256)
        ((uint4*)outp)[w] = ((const uint4*)cnt)[w];
}

// Per-bin reduce over the 64 block-partials; optionally convert partials to
// per-block exclusive prefixes in place (for the atomic-free scatter).
// One thread handles one packed word (2 bins).
__global__ void __launch_bounds__(256) hist_scan_kernel(unsigned int* __restrict__ partials,
                                                        float* __restrict__ dinv,
                                                        int* __restrict__ deg,
                                                        int do_prefix) {
    int wg = blockIdx.x * blockDim.x + threadIdx.x;     // 0 .. 4*HIST_WORDS-1
    if (wg >= 4 * HIST_WORDS) return;
    int range = wg >> 14;                               // / HIST_WORDS
    int word = wg & (HIST_WORDS - 1);
    unsigned int* base = partials + ((size_t)range * HIST_BLOCKS) * HIST_WORDS + word;
    unsigned lo = 0, hi = 0;
    for (int b = 0; b < HIST_BLOCKS; ++b) {
        unsigned c = base[(size_t)b * HIST_WORDS];
        if (do_prefix) base[(size_t)b * HIST_WORDS] = (lo & 0xffffu) | (hi << 16);
        lo += c & 0xffffu;
        hi += c >> 16;
    }
    int v0 = range * HIST_BINS + 2 * word;
    if (v0 < N_NODES) {
        dinv[v0] = lo ? rsqrtf((float)lo) : 0.0f;
        if (deg) deg[v0] = (int)lo;
    }
    int v1 = v0 + 1;
    if (v1 < N_NODES) {
        dinv[v1] = hi ? rsqrtf((float)hi) : 0.0f;
        if (deg) deg[v1] = (int)hi;
    }
}

// --------------------------- row_start scan ---------------------------------
__global__ void block_sum_kernel(const int* __restrict__ deg, int* __restrict__ partial) {
    __shared__ int s[256];
    int t = threadIdx.x;
    int i = blockIdx.x * 256 + t;
    s[t] = (i < N_NODES) ? deg[i] : 0;
    __syncthreads();
    for (int off = 128; off >= 1; off >>= 1) {
        if (t < off) s[t] += s[t + off];
        __syncthreads();
    }
    if (t == 0) partial[blockIdx.x] = s[0];
}

__global__ void scan_partial_kernel(int* partial, int* row_start) {
    if (threadIdx.x == 0 && blockIdx.x == 0) {
        int acc = 0;
        for (int b = 0; b < N_SCAN_BLOCKS; ++b) {
            int v = partial[b];
            partial[b] = acc;
            acc += v;
        }
        row_start[N_NODES] = acc;
    }
}

__global__ void row_start_kernel(const int* __restrict__ deg, const int* __restrict__ partial,
                                 int* __restrict__ row_start) {
    __shared__ int s[256];
    int t = threadIdx.x;
    int i = blockIdx.x * 256 + t;
    int v = (i < N_NODES) ? deg[i] : 0;
    s[t] = v;
    __syncthreads();
    for (int off = 1; off < 256; off <<= 1) {
        int add = (t >= off) ? s[t - off] : 0;
        __syncthreads();
        s[t] += add;
        __syncthreads();
    }
    if (i < N_NODES) row_start[i] = s[t] - v + partial[blockIdx.x];
}

// Atomic-free scatter: grid = (64 slices, 8 sub-ranges of 16384 bins).
// cursor[] initialized from row_start + per-block exclusive prefix; only
// LDS atomics for within-block ordering.
__global__ void __launch_bounds__(256) scatter_kernel(const int* __restrict__ src32,
                                                      const int* __restrict__ dst32,
                                                      const float* __restrict__ dinv_out,
                                                      const float* __restrict__ dinv_in,
                                                      const int* __restrict__ row_start,
                                                      const unsigned int* __restrict__ partials,
                                                      int2* __restrict__ csr) {
    __shared__ int cursor[SC_BINS];   // 64 KB
    int b = blockIdx.x;
    int r8 = blockIdx.y;              // sub-range
    int lo = r8 * SC_BINS;
    const unsigned int* pre = partials +
        ((size_t)((r8 >> 1) * HIST_BLOCKS + b)) * HIST_WORDS + (r8 & 1) * (SC_BINS / 2);
    for (int w = threadIdx.x; w < SC_BINS / 2; w += 256) {
        unsigned pk = pre[w];
        int v0 = lo + 2 * w;
        int v1 = v0 + 1;
        cursor[2 * w]     = (v0 < N_NODES ? row_start[v0] : 0) + (int)(pk & 0xffffu);
        cursor[2 * w + 1] = (v1 < N_NODES ? row_start[v1] : 0) + (int)(pk >> 16);
    }
    __syncthreads();
    int beg = b * EDGES_PER_HIST_BLOCK;
    int end = beg + EDGES_PER_HIST_BLOCK;
    for (int i = beg + threadIdx.x; i < end; i += 256) {
        int d = dst32[i];
        unsigned v = (unsigned)d - (unsigned)lo;
        if (v < SC_BINS) {
            int s = src32[i];
            int pos = atomicAdd(&cursor[v], 1);
            csr[pos] = make_int2(s, __float_as_int(dinv_out[s] * dinv_in[d]));
        }
    }
}

// ---------------------------------------------------------------------------
// MFMA MLP: h = relu(relu(x@W1)@W2) in bf16, f32 accumulate.
// Block = 256 threads (4 waves), 64-node tile (16 rows/wave).
// W1 staged to LDS in B-frag layout in two 32KB halves; A-frags loaded
// directly from global x (each row read exactly once, 128B/row/k-step).
__global__ void __launch_bounds__(256) mlp_kernel(const float* __restrict__ x,
                                                  const float* __restrict__ W1,
                                                  const float* __restrict__ W2,
                                                  unsigned short* __restrict__ h) {
    __shared__ __align__(16) unsigned short b1[8 * 4 * 64 * 8];   // 32 KB [t][nt][lane][j]
    __shared__ __align__(16) unsigned short b2[2 * 4 * 64 * 8];   // 8 KB
    __shared__ __align__(16) unsigned short a2s[4][2 * 64 * 8];   // 8 KB per-wave layer2 A

    int tid = threadIdx.x;
    int w = tid >> 6;
    int l = tid & 63;
    int kg = l >> 4;              // 0..3 k-group
    int m  = l & 15;              // row/col within 16
    int row = blockIdx.x * 64 + w * 16 + m;
    bool valid = row < N_NODES;
    const float* xp = x + (size_t)row * IN_F + kg * 8;

    // stage W2 once: 4096 elems, 16/thread
#pragma unroll
    for (int i = 0; i < 4; ++i) {
        int flat = i * 1024 + tid * 4;
        float4 v = *(const float4*)(W2 + flat);
        int r = flat >> 6, c0 = flat & 63;
        int t2 = r >> 5, kgs = (r >> 3) & 3, ko = r & 7;
        float vv[4] = {v.x, v.y, v.z, v.w};
#pragma unroll
        for (int q = 0; q < 4; ++q) {
            int c = c0 + q;
            b2[(((t2 * 4 + (c >> 4)) * 64) + (kgs * 16 + (c & 15))) * 8 + ko] = f2bf(vv[q]);
        }
    }

    f32x4 acc[4];
#pragma unroll
    for (int nt = 0; nt < 4; ++nt) acc[nt] = (f32x4){0.f, 0.f, 0.f, 0.f};

    for (int p = 0; p < 2; ++p) {
        __syncthreads();
        // stage 256 rows of W1 (32 KB bf16) in B-frag layout
#pragma unroll
        for (int i = 0; i < 16; ++i) {
            int flat = i * 1024 + tid * 4;
            int rl = flat >> 6;                    // local row 0..255
            int c0 = flat & 63;
            float4 v = *(const float4*)(W1 + (size_t)(p * 256 + rl) * HID + c0);
            int t = rl >> 5, kgs = (rl >> 3) & 3, ko = rl & 7;
            float vv[4] = {v.x, v.y, v.z, v.w};
#pragma unroll
            for (int q = 0; q < 4; ++q) {
                int c = c0 + q;
                b1[(((t * 4 + (c >> 4)) * 64) + (kgs * 16 + (c & 15))) * 8 + ko] = f2bf(vv[q]);
            }
        }
        __syncthreads();
#pragma unroll
        for (int t = 0; t < 8; ++t) {
            union { bf16x8 v; unsigned short u[8]; } a;
            if (valid) {
                const float* ap = xp + (p * 256 + t * 32);
                float4 u0 = *(const float4*)ap;
                float4 u1 = *(const float4*)(ap + 4);
                a.u[0] = f2bf(u0.x); a.u[1] = f2bf(u0.y);
                a.u[2] = f2bf(u0.z); a.u[3] = f2bf(u0.w);
                a.u[4] = f2bf(u1.x); a.u[5] = f2bf(u1.y);
                a.u[6] = f2bf(u1.z); a.u[7] = f2bf(u1.w);
            } else {
#pragma unroll
                for (int q = 0; q < 8; ++q) a.u[q] = 0;
            }
#pragma unroll
            for (int nt = 0; nt < 4; ++nt) {
                bf16x8 b = *(const bf16x8*)&b1[((t * 4 + nt) * 64 + l) * 8];
                acc[nt] = __builtin_amdgcn_mfma_f32_16x16x32_bf16(a.v, b, acc[nt], 0, 0, 0);
            }
        }
    }

    // relu(h1) -> bf16 -> per-wave LDS restage into layer-2 A-frag layout
#pragma unroll
    for (int nt = 0; nt < 4; ++nt) {
#pragma unroll
        for (int reg = 0; reg < 4; ++reg) {
            float v = fmaxf(acc[nt][reg], 0.0f);
            int c = nt * 16 + m;            // hid index (k of layer 2)
            int r = kg * 4 + reg;           // row within wave's 16
            a2s[w][((c >> 5) * 64 + (((c >> 3) & 3) * 16 + r)) * 8 + (c & 7)] = f2bf(v);
        }
    }

    f32x4 acc2[4];
#pragma unroll
    for (int nt = 0; nt < 4; ++nt) acc2[nt] = (f32x4){0.f, 0.f, 0.f, 0.f};
#pragma unroll
    for (int t2 = 0; t2 < 2; ++t2) {
        bf16x8 a = *(const bf16x8*)&a2s[w][(t2 * 64 + l) * 8];
#pragma unroll
        for (int nt = 0; nt < 4; ++nt) {
            bf16x8 b = *(const bf16x8*)&b2[((t2 * 4 + nt) * 64 + l) * 8];
            acc2[nt] = __builtin_amdgcn_mfma_f32_16x16x32_bf16(a, b, acc2[nt], 0, 0, 0);
        }
    }

#pragma unroll
    for (int nt = 0; nt < 4; ++nt) {
#pragma unroll
        for (int reg = 0; reg < 4; ++reg) {
            int r_out = blockIdx.x * 64 + w * 16 + kg * 4 + reg;
            if (r_out < N_NODES)
                h[(size_t)r_out * OUT_F + nt * 16 + m] = f2bf(fmaxf(acc2[nt][reg], 0.0f));
        }
    }
}

// ---------------------------------------------------------------------------
// Initial combine: out = sigmoid(h . s) * h   (h is bf16)
__global__ void __launch_bounds__(256) combine_kernel(const unsigned short* __restrict__ feat,
                                                      const float* __restrict__ sv,
                                                      float* __restrict__ out) {
    int lane = threadIdx.x & 63;
    int node = blockIdx.x * 4 + (threadIdx.x >> 6);
    if (node >= N_NODES) return;
    float v = bf2f(feat[(size_t)node * OUT_F + lane]);
    float p = v * sv[lane];
#pragma unroll
    for (int off = 32; off >= 1; off >>= 1) p += __shfl_xor(p, off, 64);
    float score = 1.0f / (1.0f + expf(-p));
    out[(size_t)node * OUT_F + lane] = score * v;
}

// ---------------------------------------------------------------------------
// One hop + fused gate-combine. One wave per dst node; 8 edge-slots x 8
// feature-lanes; bf16 feat rows (128 B, one uint4/lane); f32 accumulation.
__global__ void __launch_bounds__(256) hop_combine_kernel(
        const unsigned short* __restrict__ feat,
        const int* __restrict__ row_start,
        const int2* __restrict__ csr,
        const float* __restrict__ sv,
        unsigned short* __restrict__ fnext,
        float* __restrict__ out) {
    int lane = threadIdx.x & 63;
    int node = blockIdx.x * 4 + (threadIdx.x >> 6);
    if (node >= N_NODES) return;
    int beg = row_start[node];
    int end = row_start[node + 1];
    int slot = lane >> 3;
    int sub  = lane & 7;

    float acc[8];
#pragma unroll
    for (int j = 0; j < 8; ++j) acc[j] = 0.0f;

    for (int i = beg + slot; i < end; i += 8) {
        int2 e = csr[i];
        float nrm = __int_as_float(e.y);
        const unsigned short* fr = feat + (size_t)e.x * OUT_F + sub * 8;
        uint4 v = *(const uint4*)fr;
        acc[0] = fmaf(__uint_as_float(v.x << 16),          nrm, acc[0]);
        acc[1] = fmaf(__uint_as_float(v.x & 0xffff0000u),  nrm, acc[1]);
        acc[2] = fmaf(__uint_as_float(v.y << 16),          nrm, acc[2]);
        acc[3] = fmaf(__uint_as_float(v.y & 0xffff0000u),  nrm, acc[3]);
        acc[4] = fmaf(__uint_as_float(v.z << 16),          nrm, acc[4]);
        acc[5] = fmaf(__uint_as_float(v.z & 0xffff0000u),  nrm, acc[5]);
        acc[6] = fmaf(__uint_as_float(v.w << 16),          nrm, acc[6]);
        acc[7] = fmaf(__uint_as_float(v.w & 0xffff0000u),  nrm, acc[7]);
    }
#pragma unroll
    for (int off = 8; off <= 32; off <<= 1) {
#pragma unroll
        for (int j = 0; j < 8; ++j) acc[j] += __shfl_xor(acc[j], off, 64);
    }
    float4 s0 = *(const float4*)(sv + sub * 8);
    float4 s1 = *(const float4*)(sv + sub * 8 + 4);
    float p = acc[0] * s0.x + acc[1] * s0.y + acc[2] * s0.z + acc[3] * s0.w
            + acc[4] * s1.x + acc[5] * s1.y + acc[6] * s1.z + acc[7] * s1.w;
#pragma unroll
    for (int off = 1; off <= 4; off <<= 1) p += __shfl_xor(p, off, 64);
    float score = 1.0f / (1.0f + expf(-p));

    if (slot == 0) {
        uint4 wv;
        wv.x = (unsigned)f2bf(acc[0]) | ((unsigned)f2bf(acc[1]) << 16);
        wv.y = (unsigned)f2bf(acc[2]) | ((unsigned)f2bf(acc[3]) << 16);
        wv.z = (unsigned)f2bf(acc[4]) | ((unsigned)f2bf(acc[5]) << 16);
        wv.w = (unsigned)f2bf(acc[6]) | ((unsigned)f2bf(acc[7]) << 16);
        *(uint4*)(fnext + (size_t)node * OUT_F + sub * 8) = wv;
        float4* op = (float4*)(out + (size_t)node * OUT_F + sub * 8);
        float4 o0 = op[0], o1 = op[1];
        o0.x = fmaf(score, acc[0], o0.x);
        o0.y = fmaf(score, acc[1], o0.y);
        o0.z = fmaf(score, acc[2], o0.z);
        o0.w = fmaf(score, acc[3], o0.w);
        o1.x = fmaf(score, acc[4], o1.x);
        o1.y = fmaf(score, acc[5], o1.y);
        o1.z = fmaf(score, acc[6], o1.z);
        o1.w = fmaf(score, acc[7], o1.w);
        op[0] = o0;
        op[1] = o1;
    }
}

// ---------------------------------------------------------------------------
extern "C" void kernel_launch(void* const* d_in, const int* in_sizes, int n_in,
                              void* d_out, int out_size, void* d_ws, size_t ws_size,
                              hipStream_t stream) {
    const float* x  = (const float*)d_in[0];
    const void*  ei = d_in[1];
    const float* W1 = (const float*)d_in[2];
    const float* W2 = (const float*)d_in[3];
    const float* sv = (const float*)d_in[4];
    float* out = (float*)d_out;

    char* p = (char*)d_ws;
    auto alloc = [&](size_t bytes) -> char* {
        char* r = p;
        p += (bytes + 255) & ~(size_t)255;
        return r;
    };
    unsigned short* fA = (unsigned short*)alloc(sizeof(unsigned short) * N_NODES * OUT_F);
    unsigned short* fB = (unsigned short*)alloc(sizeof(unsigned short) * N_NODES * OUT_F);
    int*   src32     = (int*)alloc(sizeof(int) * N_EDGES);
    int*   dst32     = (int*)alloc(sizeof(int) * N_EDGES);
    int2*  csr       = (int2*)alloc(sizeof(int2) * N_EDGES);                    // 25.6 MB
    unsigned int* partials = (unsigned int*)alloc(sizeof(unsigned int) * 4 * HIST_BLOCKS * HIST_WORDS); // 16.8 MB
    int*   deg_in    = (int*)alloc(sizeof(int) * N_NODES);
    float* dinv_out  = (float*)alloc(sizeof(float) * N_NODES);
    float* dinv_in   = (float*)alloc(sizeof(float) * N_NODES);
    int*   row_start = (int*)alloc(sizeof(int) * (N_NODES + 1));
    int*   partial   = (int*)alloc(sizeof(int) * N_SCAN_BLOCKS);
    int*   flag      = (int*)alloc(256);

    hipMemsetAsync(flag, 0, sizeof(int), stream);

    detect_i32_kernel<<<4, 256, 0, stream>>>((const unsigned int*)ei, flag);
    convert_kernel<<<(N_EDGES / 2 + 255) / 256, 256, 0, stream>>>(ei, flag, src32, dst32);

    // src histogram -> dinv_out (totals only)
    hist_kernel<<<dim3(HIST_BLOCKS, 4), 256, 0, stream>>>(src32, partials);
    hist_scan_kernel<<<(4 * HIST_WORDS + 255) / 256, 256, 0, stream>>>(partials, dinv_out,
                                                                       nullptr, 0);
    // dst histogram -> deg_in, dinv_in, in-place per-block prefixes
    hist_kernel<<<dim3(HIST_BLOCKS, 4), 256, 0, stream>>>(dst32, partials);
    hist_scan_kernel<<<(4 * HIST_WORDS + 255) / 256, 256, 0, stream>>>(partials, dinv_in,
                                                                       deg_in, 1);
    block_sum_kernel<<<N_SCAN_BLOCKS, 256, 0, stream>>>(deg_in, partial);
    scan_partial_kernel<<<1, 64, 0, stream>>>(partial, row_start);
    row_start_kernel<<<N_SCAN_BLOCKS, 256, 0, stream>>>(deg_in, partial, row_start);
    scatter_kernel<<<dim3(HIST_BLOCKS, 8), 256, 0, stream>>>(src32, dst32, dinv_out, dinv_in,
                                                             row_start, partials, csr);

    int mlp_blocks = (N_NODES + 63) / 64;                   // 1563
    mlp_kernel<<<mlp_blocks, 256, 0, stream>>>(x, W1, W2, fA);

    int node_blocks = (N_NODES + 3) / 4;                    // 25000
    combine_kernel<<<node_blocks, 256, 0, stream>>>(fA, sv, out);

    unsigned short* cur = fA;
    unsigned short* nxt = fB;
    for (int hop = 0; hop < K_HOPS; ++hop) {
        hop_combine_kernel<<<node_blocks, 256, 0, stream>>>(cur, row_start, csr,
                                                            sv, nxt, out);
        unsigned short* t = cur; cur = nxt; nxt = t;
    }
}

// Round 6
// 1147.822 us; speedup vs baseline: 1.0005x; 1.0005x over previous
//
#include <hip/hip_runtime.h>
#include <hip/hip_bf16.h>

#define N_NODES 100000
#define N_EDGES 3200000
#define IN_F 512
#define HID 64
#define OUT_F 64
#define K_HOPS 10
#define N_SCAN_BLOCKS ((N_NODES + 255) / 256)   // 391

// histogram geometry: 4 ranges of 32768 bins cover 131072 >= N_NODES
#define HIST_BLOCKS 64
#define HIST_BINS 32768
#define HIST_WORDS (HIST_BINS / 2)              // 16384 packed dual-uint16 words
#define EDGES_PER_HIST_BLOCK (N_EDGES / HIST_BLOCKS)  // 50000

typedef __attribute__((ext_vector_type(8))) short bf16x8;
typedef __attribute__((ext_vector_type(4))) float f32x4;

static __device__ __forceinline__ unsigned short f2bf(float f) {
    unsigned int u = __float_as_uint(f);
    u += 0x7FFFu + ((u >> 16) & 1u);            // round-to-nearest-even
    return (unsigned short)(u >> 16);
}
static __device__ __forceinline__ float bf2f(unsigned short s) {
    return __uint_as_float(((unsigned int)s) << 16);
}

// ---------------------------------------------------------------------------
__global__ void detect_i32_kernel(const unsigned int* ei_words, int* flag_is32) {
    int i = blockIdx.x * blockDim.x + threadIdx.x;  // 0..1023
    unsigned int w = ei_words[2 * i + 1];
    if (w != 0u) atomicOr(flag_is32, 1);
}

__global__ void __launch_bounds__(256) convert_kernel(const void* ei_raw, const int* flag_is32,
                                                      int* __restrict__ src32,
                                                      int* __restrict__ dst32) {
    int t = blockIdx.x * blockDim.x + threadIdx.x;     // 0 .. N_EDGES/2-1
    if (t >= N_EDGES / 2) return;
    if (*flag_is32) {
        const int2* ei = (const int2*)ei_raw;
        *(int2*)(src32 + 2 * t) = ei[t];
        *(int2*)(dst32 + 2 * t) = ei[N_EDGES / 2 + t];
    } else {
        const longlong2* ei = (const longlong2*)ei_raw;
        longlong2 s = ei[t];
        longlong2 d = ei[N_EDGES / 2 + t];
        *(int2*)(src32 + 2 * t) = make_int2((int)s.x, (int)s.y);
        *(int2*)(dst32 + 2 * t) = make_int2((int)d.x, (int)d.y);
    }
}

// Partial histograms of both arrays in LDS (packed dual-uint16), no global
// atomics. grid = (HIST_BLOCKS slices, 8): arr = y>>2, range = y&3.
__global__ void __launch_bounds__(256) hist_kernel(const int* __restrict__ src32,
                                                   const int* __restrict__ dst32,
                                                   unsigned int* __restrict__ partials) {
    __shared__ unsigned int cnt[HIST_WORDS];   // 64 KB
    int tid = threadIdx.x;
    for (int w = tid; w < HIST_WORDS; w += 256) cnt[w] = 0u;
    __syncthreads();

    int arr = blockIdx.y >> 2;
    int range = blockIdx.y & 3;
    unsigned lo = (unsigned)(range * HIST_BINS);
    const int* a = arr ? dst32 : src32;
    int beg = blockIdx.x * EDGES_PER_HIST_BLOCK;
    int end = beg + EDGES_PER_HIST_BLOCK;
    for (int i = beg + tid; i < end; i += 256) {
        unsigned v = (unsigned)a[i] - lo;
        if (v < HIST_BINS) atomicAdd(&cnt[v >> 1], 1u << ((v & 1u) * 16u));
    }
    __syncthreads();

    unsigned int* outp = partials + ((size_t)(blockIdx.y * HIST_BLOCKS + blockIdx.x)) * HIST_WORDS;
    for (int w = tid; w < HIST_WORDS / 4; w += 256)
        ((uint4*)outp)[w] = ((const uint4*)cnt)[w];
}

// Per-bin reduce over the 64 block-partials; one thread per packed word.
// arr selects src (0: dinv only) or dst (1: dinv + deg).
__global__ void __launch_bounds__(256) hist_scan_kernel(const unsigned int* __restrict__ partials,
                                                        float* __restrict__ dinv,
                                                        int* __restrict__ deg,
                                                        int arr) {
    int wg = blockIdx.x * blockDim.x + threadIdx.x;     // 0 .. 4*HIST_WORDS-1
    if (wg >= 4 * HIST_WORDS) return;
    int range = wg >> 14;
    int word = wg & (HIST_WORDS - 1);
    const unsigned int* base = partials + ((size_t)(arr * 4 + range) * HIST_BLOCKS) * HIST_WORDS + word;
    unsigned lo = 0, hi = 0;
    for (int b = 0; b < HIST_BLOCKS; ++b) {
        unsigned c = base[(size_t)b * HIST_WORDS];
        lo += c & 0xffffu;
        hi += c >> 16;
    }
    int v0 = range * HIST_BINS + 2 * word;
    if (v0 < N_NODES) {
        dinv[v0] = lo ? rsqrtf((float)lo) : 0.0f;
        if (deg) deg[v0] = (int)lo;
    }
    int v1 = v0 + 1;
    if (v1 < N_NODES) {
        dinv[v1] = hi ? rsqrtf((float)hi) : 0.0f;
        if (deg) deg[v1] = (int)hi;
    }
}

// --------------------------- row_start scan ---------------------------------
__global__ void block_sum_kernel(const int* __restrict__ deg, int* __restrict__ partial) {
    __shared__ int s[256];
    int t = threadIdx.x;
    int i = blockIdx.x * 256 + t;
    s[t] = (i < N_NODES) ? deg[i] : 0;
    __syncthreads();
    for (int off = 128; off >= 1; off >>= 1) {
        if (t < off) s[t] += s[t + off];
        __syncthreads();
    }
    if (t == 0) partial[blockIdx.x] = s[0];
}

__global__ void scan_partial_kernel(int* partial, int* row_start) {
    if (threadIdx.x == 0 && blockIdx.x == 0) {
        int acc = 0;
        for (int b = 0; b < N_SCAN_BLOCKS; ++b) {
            int v = partial[b];
            partial[b] = acc;
            acc += v;
        }
        row_start[N_NODES] = acc;
    }
}

__global__ void row_start_kernel(const int* __restrict__ deg, const int* __restrict__ partial,
                                 int* __restrict__ row_start, int* __restrict__ cursor) {
    __shared__ int s[256];
    int t = threadIdx.x;
    int i = blockIdx.x * 256 + t;
    int v = (i < N_NODES) ? deg[i] : 0;
    s[t] = v;
    __syncthreads();
    for (int off = 1; off < 256; off <<= 1) {
        int add = (t >= off) ? s[t - off] : 0;
        __syncthreads();
        s[t] += add;
        __syncthreads();
    }
    if (i < N_NODES) {
        int excl = s[t] - v + partial[blockIdx.x];
        row_start[i] = excl;
        cursor[i] = excl;
    }
}

// Streaming norm precompute: keeps the dinv gathers out of the scatter chain.
__global__ void __launch_bounds__(256) norm_kernel(const int* __restrict__ src32,
                                                   const int* __restrict__ dst32,
                                                   const float* __restrict__ dinv_out,
                                                   const float* __restrict__ dinv_in,
                                                   float* __restrict__ norm) {
    int e = blockIdx.x * blockDim.x + threadIdx.x;
    if (e >= N_EDGES) return;
    norm[e] = dinv_out[src32[e]] * dinv_in[dst32[e]];
}

// Single-pass scatter with global-atomic cursors (full occupancy).
__global__ void __launch_bounds__(256) scatter_kernel(const int* __restrict__ src32,
                                                      const int* __restrict__ dst32,
                                                      const float* __restrict__ norm,
                                                      int* __restrict__ cursor,
                                                      int2* __restrict__ csr) {
    int e = blockIdx.x * blockDim.x + threadIdx.x;
    if (e >= N_EDGES) return;
    int d = dst32[e];
    int pos = atomicAdd(&cursor[d], 1);
    csr[pos] = make_int2(src32[e], __float_as_int(norm[e]));
}

// ---------------------------------------------------------------------------
// MFMA MLP: h = relu(relu(x@W1)@W2) in bf16, f32 accumulate.
__global__ void __launch_bounds__(256) mlp_kernel(const float* __restrict__ x,
                                                  const float* __restrict__ W1,
                                                  const float* __restrict__ W2,
                                                  unsigned short* __restrict__ h) {
    __shared__ __align__(16) unsigned short b1[8 * 4 * 64 * 8];   // 32 KB [t][nt][lane][j]
    __shared__ __align__(16) unsigned short b2[2 * 4 * 64 * 8];   // 8 KB
    __shared__ __align__(16) unsigned short a2s[4][2 * 64 * 8];   // 8 KB per-wave layer2 A

    int tid = threadIdx.x;
    int w = tid >> 6;
    int l = tid & 63;
    int kg = l >> 4;
    int m  = l & 15;
    int row = blockIdx.x * 64 + w * 16 + m;
    bool valid = row < N_NODES;
    const float* xp = x + (size_t)row * IN_F + kg * 8;

#pragma unroll
    for (int i = 0; i < 4; ++i) {
        int flat = i * 1024 + tid * 4;
        float4 v = *(const float4*)(W2 + flat);
        int r = flat >> 6, c0 = flat & 63;
        int t2 = r >> 5, kgs = (r >> 3) & 3, ko = r & 7;
        float vv[4] = {v.x, v.y, v.z, v.w};
#pragma unroll
        for (int q = 0; q < 4; ++q) {
            int c = c0 + q;
            b2[(((t2 * 4 + (c >> 4)) * 64) + (kgs * 16 + (c & 15))) * 8 + ko] = f2bf(vv[q]);
        }
    }

    f32x4 acc[4];
#pragma unroll
    for (int nt = 0; nt < 4; ++nt) acc[nt] = (f32x4){0.f, 0.f, 0.f, 0.f};

    for (int p = 0; p < 2; ++p) {
        __syncthreads();
#pragma unroll
        for (int i = 0; i < 16; ++i) {
            int flat = i * 1024 + tid * 4;
            int rl = flat >> 6;
            int c0 = flat & 63;
            float4 v = *(const float4*)(W1 + (size_t)(p * 256 + rl) * HID + c0);
            int t = rl >> 5, kgs = (rl >> 3) & 3, ko = rl & 7;
            float vv[4] = {v.x, v.y, v.z, v.w};
#pragma unroll
            for (int q = 0; q < 4; ++q) {
                int c = c0 + q;
                b1[(((t * 4 + (c >> 4)) * 64) + (kgs * 16 + (c & 15))) * 8 + ko] = f2bf(vv[q]);
            }
        }
        __syncthreads();
#pragma unroll
        for (int t = 0; t < 8; ++t) {
            union { bf16x8 v; unsigned short u[8]; } a;
            if (valid) {
                const float* ap = xp + (p * 256 + t * 32);
                float4 u0 = *(const float4*)ap;
                float4 u1 = *(const float4*)(ap + 4);
                a.u[0] = f2bf(u0.x); a.u[1] = f2bf(u0.y);
                a.u[2] = f2bf(u0.z); a.u[3] = f2bf(u0.w);
                a.u[4] = f2bf(u1.x); a.u[5] = f2bf(u1.y);
                a.u[6] = f2bf(u1.z); a.u[7] = f2bf(u1.w);
            } else {
#pragma unroll
                for (int q = 0; q < 8; ++q) a.u[q] = 0;
            }
#pragma unroll
            for (int nt = 0; nt < 4; ++nt) {
                bf16x8 b = *(const bf16x8*)&b1[((t * 4 + nt) * 64 + l) * 8];
                acc[nt] = __builtin_amdgcn_mfma_f32_16x16x32_bf16(a.v, b, acc[nt], 0, 0, 0);
            }
        }
    }

#pragma unroll
    for (int nt = 0; nt < 4; ++nt) {
#pragma unroll
        for (int reg = 0; reg < 4; ++reg) {
            float v = fmaxf(acc[nt][reg], 0.0f);
            int c = nt * 16 + m;
            int r = kg * 4 + reg;
            a2s[w][((c >> 5) * 64 + (((c >> 3) & 3) * 16 + r)) * 8 + (c & 7)] = f2bf(v);
        }
    }

    f32x4 acc2[4];
#pragma unroll
    for (int nt = 0; nt < 4; ++nt) acc2[nt] = (f32x4){0.f, 0.f, 0.f, 0.f};
#pragma unroll
    for (int t2 = 0; t2 < 2; ++t2) {
        bf16x8 a = *(const bf16x8*)&a2s[w][(t2 * 64 + l) * 8];
#pragma unroll
        for (int nt = 0; nt < 4; ++nt) {
            bf16x8 b = *(const bf16x8*)&b2[((t2 * 4 + nt) * 64 + l) * 8];
            acc2[nt] = __builtin_amdgcn_mfma_f32_16x16x32_bf16(a, b, acc2[nt], 0, 0, 0);
        }
    }

#pragma unroll
    for (int nt = 0; nt < 4; ++nt) {
#pragma unroll
        for (int reg = 0; reg < 4; ++reg) {
            int r_out = blockIdx.x * 64 + w * 16 + kg * 4 + reg;
            if (r_out < N_NODES)
                h[(size_t)r_out * OUT_F + nt * 16 + m] = f2bf(fmaxf(acc2[reg < 0 ? 0 : nt][reg], 0.0f));
        }
    }
}

// ---------------------------------------------------------------------------
// Initial combine: out = sigmoid(h . s) * h   (h is bf16)
__global__ void __launch_bounds__(256) combine_kernel(const unsigned short* __restrict__ feat,
                                                      const float* __restrict__ sv,
                                                      float* __restrict__ out) {
    int lane = threadIdx.x & 63;
    int node = blockIdx.x * 4 + (threadIdx.x >> 6);
    if (node >= N_NODES) return;
    float v = bf2f(feat[(size_t)node * OUT_F + lane]);
    float p = v * sv[lane];
#pragma unroll
    for (int off = 32; off >= 1; off >>= 1) p += __shfl_xor(p, off, 64);
    float score = 1.0f / (1.0f + expf(-p));
    out[(size_t)node * OUT_F + lane] = score * v;
}

// ---------------------------------------------------------------------------
// One hop + fused gate-combine.  One wave per dst node.
// Coalesced preload of 64 CSR entries/wave, then up to 8 independent
// feat-row gathers issued back-to-back (8 edge-slots x 8 feature-lanes).
__global__ void __launch_bounds__(256) hop_combine_kernel(
        const unsigned short* __restrict__ feat,
        const int* __restrict__ row_start,
        const int2* __restrict__ csr,
        const float* __restrict__ sv,
        unsigned short* __restrict__ fnext,
        float* __restrict__ out) {
    int lane = threadIdx.x & 63;
    int node = blockIdx.x * 4 + (threadIdx.x >> 6);
    if (node >= N_NODES) return;
    int beg = row_start[node];
    int end = row_start[node + 1];
    int slot = lane >> 3;    // 0..7: edge slot
    int sub  = lane & 7;     // feature group: features 8*sub..8*sub+7

    float acc[8];
#pragma unroll
    for (int j = 0; j < 8; ++j) acc[j] = 0.0f;

    for (int chunk = beg; chunk < end; chunk += 64) {
        int nrem = end - chunk;                       // wave-uniform
        int2 ce = make_int2(0, 0);                    // pad: src 0, norm 0.0
        if (chunk + lane < end) ce = csr[chunk + lane];   // coalesced 512B/wave

        uint4 v[8];
        float nrm[8];
#pragma unroll
        for (int g = 0; g < 8; ++g) {
            if (g * 8 < nrem) {                       // uniform branch
                int esrc = __shfl(ce.x, g * 8 + slot, 64);
                nrm[g] = __uint_as_float((unsigned)__shfl(ce.y, g * 8 + slot, 64));
                v[g] = *(const uint4*)(feat + (size_t)esrc * OUT_F + sub * 8);
            }
        }
#pragma unroll
        for (int g = 0; g < 8; ++g) {
            if (g * 8 < nrem) {
                acc[0] = fmaf(__uint_as_float(v[g].x << 16),         nrm[g], acc[0]);
                acc[1] = fmaf(__uint_as_float(v[g].x & 0xffff0000u), nrm[g], acc[1]);
                acc[2] = fmaf(__uint_as_float(v[g].y << 16),         nrm[g], acc[2]);
                acc[3] = fmaf(__uint_as_float(v[g].y & 0xffff0000u), nrm[g], acc[3]);
                acc[4] = fmaf(__uint_as_float(v[g].z << 16),         nrm[g], acc[4]);
                acc[5] = fmaf(__uint_as_float(v[g].z & 0xffff0000u), nrm[g], acc[5]);
                acc[6] = fmaf(__uint_as_float(v[g].w << 16),         nrm[g], acc[6]);
                acc[7] = fmaf(__uint_as_float(v[g].w & 0xffff0000u), nrm[g], acc[7]);
            }
        }
    }
#pragma unroll
    for (int off = 8; off <= 32; off <<= 1) {
#pragma unroll
        for (int j = 0; j < 8; ++j) acc[j] += __shfl_xor(acc[j], off, 64);
    }
    float4 s0 = *(const float4*)(sv + sub * 8);
    float4 s1 = *(const float4*)(sv + sub * 8 + 4);
    float p = acc[0] * s0.x + acc[1] * s0.y + acc[2] * s0.z + acc[3] * s0.w
            + acc[4] * s1.x + acc[5] * s1.y + acc[6] * s1.z + acc[7] * s1.w;
#pragma unroll
    for (int off = 1; off <= 4; off <<= 1) p += __shfl_xor(p, off, 64);
    float score = 1.0f / (1.0f + expf(-p));

    if (slot == 0) {          // lanes 0..7: write fnext row (bf16, 128B)
        uint4 wv;
        wv.x = (unsigned)f2bf(acc[0]) | ((unsigned)f2bf(acc[1]) << 16);
        wv.y = (unsigned)f2bf(acc[2]) | ((unsigned)f2bf(acc[3]) << 16);
        wv.z = (unsigned)f2bf(acc[4]) | ((unsigned)f2bf(acc[5]) << 16);
        wv.w = (unsigned)f2bf(acc[6]) | ((unsigned)f2bf(acc[7]) << 16);
        *(uint4*)(fnext + (size_t)node * OUT_F + sub * 8) = wv;
    } else if (slot == 1) {   // lanes 8..15: rmw out row (f32, 256B)
        float4* op = (float4*)(out + (size_t)node * OUT_F + sub * 8);
        float4 o0 = op[0], o1 = op[1];
        o0.x = fmaf(score, acc[0], o0.x);
        o0.y = fmaf(score, acc[1], o0.y);
        o0.z = fmaf(score, acc[2], o0.z);
        o0.w = fmaf(score, acc[3], o0.w);
        o1.x = fmaf(score, acc[4], o1.x);
        o1.y = fmaf(score, acc[5], o1.y);
        o1.z = fmaf(score, acc[6], o1.z);
        o1.w = fmaf(score, acc[7], o1.w);
        op[0] = o0;
        op[1] = o1;
    }
}

// ---------------------------------------------------------------------------
extern "C" void kernel_launch(void* const* d_in, const int* in_sizes, int n_in,
                              void* d_out, int out_size, void* d_ws, size_t ws_size,
                              hipStream_t stream) {
    const float* x  = (const float*)d_in[0];
    const void*  ei = d_in[1];
    const float* W1 = (const float*)d_in[2];
    const float* W2 = (const float*)d_in[3];
    const float* sv = (const float*)d_in[4];
    float* out = (float*)d_out;

    char* p = (char*)d_ws;
    auto alloc = [&](size_t bytes) -> char* {
        char* r = p;
        p += (bytes + 255) & ~(size_t)255;
        return r;
    };
    unsigned short* fA = (unsigned short*)alloc(sizeof(unsigned short) * N_NODES * OUT_F);
    unsigned short* fB = (unsigned short*)alloc(sizeof(unsigned short) * N_NODES * OUT_F);
    int*   src32     = (int*)alloc(sizeof(int) * N_EDGES);
    int*   dst32     = (int*)alloc(sizeof(int) * N_EDGES);
    int2*  csr       = (int2*)alloc(sizeof(int2) * N_EDGES);                    // 25.6 MB
    // partials (33.5 MB) dead after the scans; norm (12.8 MB) aliases it.
    char*  shared_region = alloc(sizeof(unsigned int) * 8 * HIST_BLOCKS * HIST_WORDS);
    unsigned int* partials = (unsigned int*)shared_region;
    float* norm      = (float*)shared_region;
    int*   deg_in    = (int*)alloc(sizeof(int) * N_NODES);
    float* dinv_out  = (float*)alloc(sizeof(float) * N_NODES);
    float* dinv_in   = (float*)alloc(sizeof(float) * N_NODES);
    int*   row_start = (int*)alloc(sizeof(int) * (N_NODES + 1));
    int*   cursor    = (int*)alloc(sizeof(int) * N_NODES);
    int*   partial   = (int*)alloc(sizeof(int) * N_SCAN_BLOCKS);
    int*   flag      = (int*)alloc(256);

    hipMemsetAsync(flag, 0, sizeof(int), stream);

    detect_i32_kernel<<<4, 256, 0, stream>>>((const unsigned int*)ei, flag);
    convert_kernel<<<(N_EDGES / 2 + 255) / 256, 256, 0, stream>>>(ei, flag, src32, dst32);

    hist_kernel<<<dim3(HIST_BLOCKS, 8), 256, 0, stream>>>(src32, dst32, partials);
    hist_scan_kernel<<<(4 * HIST_WORDS + 255) / 256, 256, 0, stream>>>(partials, dinv_out,
                                                                       nullptr, 0);
    hist_scan_kernel<<<(4 * HIST_WORDS + 255) / 256, 256, 0, stream>>>(partials, dinv_in,
                                                                       deg_in, 1);
    block_sum_kernel<<<N_SCAN_BLOCKS, 256, 0, stream>>>(deg_in, partial);
    scan_partial_kernel<<<1, 64, 0, stream>>>(partial, row_start);
    row_start_kernel<<<N_SCAN_BLOCKS, 256, 0, stream>>>(deg_in, partial, row_start, cursor);
    norm_kernel<<<(N_EDGES + 255) / 256, 256, 0, stream>>>(src32, dst32, dinv_out, dinv_in, norm);
    scatter_kernel<<<(N_EDGES + 255) / 256, 256, 0, stream>>>(src32, dst32, norm, cursor, csr);

    int mlp_blocks = (N_NODES + 63) / 64;                   // 1563
    mlp_kernel<<<mlp_blocks, 256, 0, stream>>>(x, W1, W2, fA);

    int node_blocks = (N_NODES + 3) / 4;                    // 25000
    combine_kernel<<<node_blocks, 256, 0, stream>>>(fA, sv, out);

    unsigned short* cur = fA;
    unsigned short* nxt = fB;
    for (int hop = 0; hop < K_HOPS; ++hop) {
        hop_combine_kernel<<<node_blocks, 256, 0, stream>>>(cur, row_start, csr,
                                                            sv, nxt, out);
        unsigned short* t = cur; cur = nxt; nxt = t;
    }
}